// Round 1
// baseline (142.559 us; speedup 1.0000x reference)
//
#include <hip/hip_runtime.h>

#define LOG100 4.605170185988091f

typedef _Float16 half8 __attribute__((ext_vector_type(8)));
typedef float f32x16 __attribute__((ext_vector_type(16)));

// ---------------- bias transpose pre-kernel: biasT[h][m][n] = bias[h][n][m] ----
__global__ __launch_bounds__(256) void bias_transpose(const float* __restrict__ bias,
                                                      float* __restrict__ biasT) {
  __shared__ float tile[32][33];
  const int head = blockIdx.z;
  const int m0 = blockIdx.x * 32;  // kv
  const int n0 = blockIdx.y * 32;  // q
  const float* src = bias + head * 65536;
  float* dst = biasT + head * 65536;
  const int tx = threadIdx.x, ty = threadIdx.y;  // (32,8)
#pragma unroll
  for (int i = ty; i < 32; i += 8) tile[i][tx] = src[(n0 + i) * 256 + m0 + tx];
  __syncthreads();
#pragma unroll
  for (int i = ty; i < 32; i += 8) dst[(m0 + i) * 256 + n0 + tx] = tile[tx][i];
}

// ---------------- main attention kernel --------------------------------------
// block = (b,h); 512 threads = 8 waves; wave w owns q rows [w*32, w*32+32)
template <bool USE_BT>
__global__ __launch_bounds__(512, 4) void attn_kernel(
    const float* __restrict__ q, const float* __restrict__ k, const float* __restrict__ v,
    const float* __restrict__ logit_scale, const float* __restrict__ bias,
    const float* __restrict__ biasT, float* __restrict__ out) {
  __shared__ __align__(16) char smem[65536];
  _Float16* Kn = (_Float16*)smem;             // [256][64] fp16, 128B rows, XOR swizzle (row&7)<<4
  _Float16* Vt = (_Float16*)(smem + 32768);   // [64][256] fp16, 512B rows, XOR swizzle (d&7)<<4

  const int tid = threadIdx.x;
  const int wave = tid >> 6;
  const int lane = tid & 63;
  const int l31 = lane & 31;
  const int hi = lane >> 5;  // 0/1
  const int head = blockIdx.x;
  const int b = blockIdx.y;

  const long base = ((long)(b * 8 + head)) * (256 * 64);
  const float* qp = q + base;
  const float* kp = k + base;
  const float* vp = v + base;

  const float scale = __expf(fminf(logit_scale[head], LOG100));

  // ---- stage K, L2-normalized, fp16, swizzled ----
  {
    const int row_in = tid >> 4;  // 0..31
    const int seg = tid & 15;     // 16 segs * 4 floats = 64
#pragma unroll
    for (int it = 0; it < 8; ++it) {
      const int row = it * 32 + row_in;
      const float4 a = *(const float4*)(kp + row * 64 + seg * 4);
      float ss = a.x * a.x + a.y * a.y + a.z * a.z + a.w * a.w;
      ss += __shfl_xor(ss, 1);
      ss += __shfl_xor(ss, 2);
      ss += __shfl_xor(ss, 4);
      ss += __shfl_xor(ss, 8);
      const float inv = rsqrtf(fmaxf(ss, 1e-24f));
      union { _Float16 h[4]; uint2 u; } pk4;
      pk4.h[0] = (_Float16)(a.x * inv);
      pk4.h[1] = (_Float16)(a.y * inv);
      pk4.h[2] = (_Float16)(a.z * inv);
      pk4.h[3] = (_Float16)(a.w * inv);
      char* wp = (char*)Kn + row * 128 + ((seg * 8) ^ ((row & 7) << 4));
      *(uint2*)wp = pk4.u;
    }
  }

  // ---- stage V transposed: Vt[d][kv], via in-register 4x4 transpose ----
  {
    const int r = lane >> 4;  // 0..3
    const int sx = lane & 15;
#pragma unroll
    for (int it = 0; it < 8; ++it) {
      const int slab = wave * 8 + it;  // 0..63, 4 kv rows each
      const int kv0 = slab * 4;
      float4 a = *(const float4*)(vp + (kv0 + r) * 64 + sx * 4);
      // transpose 4x4 across lanes {sx, sx+16, sx+32, sx+48}
      float e1 = (r & 1) ? a.x : a.y;
      float g1 = __shfl_xor(e1, 16);
      float e2 = (r & 1) ? a.z : a.w;
      float g2 = __shfl_xor(e2, 16);
      if (r & 1) { a.x = g1; a.z = g2; } else { a.y = g1; a.w = g2; }
      float e3 = (r & 2) ? a.x : a.z;
      float g3 = __shfl_xor(e3, 32);
      float e4 = (r & 2) ? a.y : a.w;
      float g4 = __shfl_xor(e4, 32);
      if (r & 2) { a.x = g3; a.y = g4; } else { a.z = g3; a.w = g4; }
      // lane now holds V[kv0+0..3][d] with d = 4*sx + r
      const int d = 4 * sx + r;
      union { _Float16 h[4]; uint2 u; } pk4;
      pk4.h[0] = (_Float16)a.x;
      pk4.h[1] = (_Float16)a.y;
      pk4.h[2] = (_Float16)a.z;
      pk4.h[3] = (_Float16)a.w;
      char* wp = (char*)Vt + d * 512 + ((kv0 * 2) ^ ((d & 7) << 4));
      *(uint2*)wp = pk4.u;
    }
  }

  // ---- load + normalize Q into B-frags (registers) ----
  // B-frag (32x32x16): lane holds q-col = l31, d = dk*16 + hi*8 + b
  const int qrow = wave * 32 + l31;
  float qf[4][8];
  float ssq = 0.f;
#pragma unroll
  for (int dk = 0; dk < 4; ++dk) {
    const float4 x0 = *(const float4*)(qp + qrow * 64 + dk * 16 + hi * 8);
    const float4 x1 = *(const float4*)(qp + qrow * 64 + dk * 16 + hi * 8 + 4);
    qf[dk][0] = x0.x; qf[dk][1] = x0.y; qf[dk][2] = x0.z; qf[dk][3] = x0.w;
    qf[dk][4] = x1.x; qf[dk][5] = x1.y; qf[dk][6] = x1.z; qf[dk][7] = x1.w;
    ssq += x0.x * x0.x + x0.y * x0.y + x0.z * x0.z + x0.w * x0.w;
    ssq += x1.x * x1.x + x1.y * x1.y + x1.z * x1.z + x1.w * x1.w;
  }
  ssq += __shfl_xor(ssq, 32);
  const float qinv = rsqrtf(fmaxf(ssq, 1e-24f));
  half8 qfrag[4];
#pragma unroll
  for (int dk = 0; dk < 4; ++dk)
#pragma unroll
    for (int j = 0; j < 8; ++j) qfrag[dk][j] = (_Float16)(qf[dk][j] * qinv);

  __syncthreads();

  // ---- kv loop: chunks of 32 ----
  f32x16 o0 = {};  // O^T d-tile 0 (d = 0..31): C layout: col=q=l31, row=d
  f32x16 o1 = {};  // O^T d-tile 1 (d = 32..63)
  float m = -3.0e38f, lsum = 0.f;

  const float* bT;
  if (USE_BT)
    bT = biasT + head * 65536 + (4 * hi) * 256 + qrow;  // + (c*32+kvr)*256
  else
    bT = bias + head * 65536 + qrow * 256 + 4 * hi;     // + (c*32+kvr)

  for (int c = 0; c < 8; ++c) {
    // K A-frags: A[i=kv][k=d]: lane: kv = c*32 + l31, d = dk*16 + hi*8 + b
    const int krow = c * 32 + l31;
    const char* kbase = (const char*)Kn + krow * 128;
    const int kmsk = (krow & 7) << 4;
    half8 kf[4];
#pragma unroll
    for (int dk = 0; dk < 4; ++dk)
      kf[dk] = *(const half8*)(kbase + ((dk * 32 + hi * 16) ^ kmsk));

    f32x16 s = {};
#pragma unroll
    for (int dk = 0; dk < 4; ++dk)
      s = __builtin_amdgcn_mfma_f32_32x32x16_f16(kf[dk], qfrag[dk], s, 0, 0, 0);

    // s[reg] = S^T[kv = c*32 + (reg&3) + 8*(reg>>2) + 4*hi][q = qrow]
    float mx = -3.0e38f;
#pragma unroll
    for (int reg = 0; reg < 16; ++reg) {
      const int kvr = (reg & 3) + 8 * (reg >> 2);
      const float bv = USE_BT ? bT[(c * 32 + kvr) * 256] : bT[c * 32 + kvr];
      const float sv = fmaf(s[reg], scale, bv);
      s[reg] = sv;
      mx = fmaxf(mx, sv);
    }
    mx = fmaxf(mx, __shfl_xor(mx, 32));
    const float mnew = fmaxf(m, mx);
    const float corr = __expf(m - mnew);
    float psum = 0.f;
#pragma unroll
    for (int reg = 0; reg < 16; ++reg) {
      const float p = __expf(s[reg] - mnew);
      s[reg] = p;
      psum += p;
    }
    psum += __shfl_xor(psum, 32);
    lsum = fmaf(lsum, corr, psum);
#pragma unroll
    for (int i = 0; i < 16; ++i) { o0[i] *= corr; o1[i] *= corr; }
    m = mnew;

    // pack P (f32 -> fp16 pairs); pk[i] = (p[2i], p[2i+1]) at kv = c*32 + 8*(i>>1) + 4*hi + 2*(i&1)
    unsigned pk[8];
#pragma unroll
    for (int i = 0; i < 8; ++i)
      pk[i] = __builtin_bit_cast(unsigned, __builtin_amdgcn_cvt_pkrtz(s[2 * i], s[2 * i + 1]));
    // exchange with lane^32 to assemble B-frags: frag ks holds kv = c*32 + ks*16 + hi*8 + b
    const unsigned ra = __shfl_xor(hi ? pk[0] : pk[2], 32);
    const unsigned rb = __shfl_xor(hi ? pk[1] : pk[3], 32);
    const unsigned rc = __shfl_xor(hi ? pk[4] : pk[6], 32);
    const unsigned rd = __shfl_xor(hi ? pk[5] : pk[7], 32);
    union { unsigned u[4]; half8 h; } f0, f1;
    f0.u[0] = hi ? ra : pk[0];
    f0.u[1] = hi ? rb : pk[1];
    f0.u[2] = hi ? pk[2] : ra;
    f0.u[3] = hi ? pk[3] : rb;
    f1.u[0] = hi ? rc : pk[4];
    f1.u[1] = hi ? rd : pk[5];
    f1.u[2] = hi ? pk[6] : rc;
    f1.u[3] = hi ? pk[7] : rd;

    // PV: O^T[d][q] += V^T[d][kv] * P^T[kv][q]
    {
      const int d = l31;  // d-tile 0
      const char* vbase = (const char*)Vt + d * 512;
      const int msk = (d & 7) << 4;
      const half8 vf0 = *(const half8*)(vbase + ((c * 64 + hi * 16) ^ msk));
      const half8 vf1 = *(const half8*)(vbase + ((c * 64 + 32 + hi * 16) ^ msk));
      o0 = __builtin_amdgcn_mfma_f32_32x32x16_f16(vf0, f0.h, o0, 0, 0, 0);
      o0 = __builtin_amdgcn_mfma_f32_32x32x16_f16(vf1, f1.h, o0, 0, 0, 0);
    }
    {
      const int d = 32 + l31;  // d-tile 1
      const char* vbase = (const char*)Vt + d * 512;
      const int msk = (d & 7) << 4;
      const half8 vf0 = *(const half8*)(vbase + ((c * 64 + hi * 16) ^ msk));
      const half8 vf1 = *(const half8*)(vbase + ((c * 64 + 32 + hi * 16) ^ msk));
      o1 = __builtin_amdgcn_mfma_f32_32x32x16_f16(vf0, f0.h, o1, 0, 0, 0);
      o1 = __builtin_amdgcn_mfma_f32_32x32x16_f16(vf1, f1.h, o1, 0, 0, 0);
    }
  }

  __syncthreads();  // all waves done reading Kn/Vt; reuse smem for output staging

  // ---- epilogue: O^T -> per-wave LDS buffer -> coalesced global stores ----
  float* ob = (float*)smem + wave * 2048;  // [32 q][64 d] f32, swizzle (q&7)<<2 on float idx
  const float invl = 1.0f / lsum;
#pragma unroll
  for (int reg = 0; reg < 16; ++reg) {
    const int d0 = (reg & 3) + 8 * (reg >> 2) + 4 * hi;
    ob[l31 * 64 + (d0 ^ ((l31 & 7) << 2))] = o0[reg] * invl;
    const int d1 = d0 + 32;
    ob[l31 * 64 + (d1 ^ ((l31 & 7) << 2))] = o1[reg] * invl;
  }
  __asm__ __volatile__("s_waitcnt lgkmcnt(0)" ::: "memory");
  __builtin_amdgcn_sched_barrier(0);
  const int sx = lane & 15;
  const int rr = lane >> 4;
#pragma unroll
  for (int kq = 0; kq < 8; ++kq) {
    const int qq = kq * 4 + rr;  // 0..31
    const float4 val = *(const float4*)(ob + qq * 64 + ((4 * sx) ^ ((qq & 7) << 2)));
    *(float4*)(out + (((long)(b * 256 + wave * 32 + qq) * 8 + head) * 64 + 4 * sx)) = val;
  }
}

extern "C" void kernel_launch(void* const* d_in, const int* in_sizes, int n_in,
                              void* d_out, int out_size, void* d_ws, size_t ws_size,
                              hipStream_t stream) {
  (void)in_sizes; (void)n_in; (void)out_size;
  const float* q = (const float*)d_in[0];
  const float* k = (const float*)d_in[1];
  const float* v = (const float*)d_in[2];
  const float* ls = (const float*)d_in[3];
  const float* bias = (const float*)d_in[4];
  float* out = (float*)d_out;
  const size_t btBytes = (size_t)8 * 256 * 256 * 4;  // 2 MB
  if (ws_size >= btBytes) {
    float* biasT = (float*)d_ws;
    bias_transpose<<<dim3(8, 8, 8), dim3(32, 8), 0, stream>>>(bias, biasT);
    attn_kernel<true><<<dim3(8, 256), dim3(512), 0, stream>>>(q, k, v, ls, bias, biasT, out);
  } else {
    attn_kernel<false><<<dim3(8, 256), dim3(512), 0, stream>>>(q, k, v, ls, bias, nullptr, out);
  }
}